// Round 10
// baseline (126.078 us; speedup 1.0000x reference)
//
#include <hip/hip_runtime.h>

typedef _Float16 f16;
typedef _Float16 f16x8 __attribute__((ext_vector_type(8)));
typedef float v4f __attribute__((ext_vector_type(4)));

__global__ __launch_bounds__(256, 4) void model_one(
    const float* __restrict__ x, const float* __restrict__ y, const float* __restrict__ t,
    const float* __restrict__ embW1, const float* __restrict__ embb1,
    const float* __restrict__ embwa, const float* __restrict__ embwb,
    const float* __restrict__ embW2, const float* __restrict__ embb2,
    const float* __restrict__ mixW1, const float* __restrict__ mixb1,
    const float* __restrict__ mixwa, const float* __restrict__ mixwb,
    const float* __restrict__ mixW2, const float* __restrict__ mixb2,
    const float* __restrict__ outW0, const float* __restrict__ outb0,
    const float* __restrict__ outwa0, const float* __restrict__ outwb0,
    const float* __restrict__ outWh, const float* __restrict__ outbh,
    const float* __restrict__ outwah, const float* __restrict__ outwbh,
    const float* __restrict__ outWf1, const float* __restrict__ outbf1,
    const float* __restrict__ outwaf, const float* __restrict__ outwbf,
    const float* __restrict__ outWf2, const float* __restrict__ outbf2,
    float* __restrict__ out, int N)
{
    __shared__ __attribute__((aligned(16))) f16 sA[16*72];     // [m=s*4+r][k]
    __shared__ __attribute__((aligned(16))) f16 sE[16*264];    // [s][c] rows 0-3 valid
    __shared__ __attribute__((aligned(16))) f16 sH[2][16*72];  // [s][f] rows 0-3 valid
    __shared__ float sHf[4*65];

    const int tid  = threadIdx.x;
    const int lane = tid & 63;
    const int wv   = tid >> 6;
    const int n0   = blockIdx.x * 4;

    // ---- phase 1: wave wv = sample wv; lane = channel k. C-factors recomputed
    //      per lane (symmetric perturbation grid collapse: <sin d>=0, <cos d>
    //      factorizes per axis) — ~18 cosf, cheaper than a second dispatch. ----
    {
        const int k = lane;
        const float w0 = embW1[k], w1 = embW1[64+k], w2 = embW1[128+k];
        const float b1 = embb1[k];
        const float ga = (1.f + 2.f*__cosf(0.01f*w0))
                       * (1.f + 2.f*__cosf(0.01f*w1))
                       * (1.f + 2.f*__cosf(0.01f*w2)) * (1.f/27.f);
        const float gb = (1.f + 2.f*(__cosf(0.025f*w0) + __cosf(0.05f*w0)))
                       * (1.f + 2.f*(__cosf(0.025f*w1) + __cosf(0.05f*w1)))
                       * (1.f + 2.f*(__cosf(0.025f*w2) + __cosf(0.05f*w2))) * (1.f/125.f);
        const float gc = (1.f + 2.f*(__cosf(0.03f*w0) + __cosf(0.06f*w0) + __cosf(0.09f*w0)))
                       * (1.f + 2.f*(__cosf(0.03f*w1) + __cosf(0.06f*w1) + __cosf(0.09f*w1)))
                       * (1.f + 2.f*(__cosf(0.03f*w2) + __cosf(0.06f*w2) + __cosf(0.09f*w2))) * (1.f/343.f);
        const int ns = (n0 + wv < N) ? (n0 + wv) : (N - 1);
        const float u = fmaf(x[ns], w0, fmaf(y[ns], w1, fmaf(t[ns], w2, b1)));
        const float sv = embwa[0]*__sinf(u) + embwb[0]*__cosf(u);
        f16* row = sA + (wv*4)*72 + k;
        row[0]   = (f16)sv;
        row[72]  = (f16)(sv*ga);
        row[144] = (f16)(sv*gb);
        row[216] = (f16)(sv*gc);
    }
    __syncthreads();

    const int l15 = lane & 15, qb = lane >> 4;

    // ---- phase 2: [16 x 64] @ embW2 [64 x 256]; wave wv owns cols wv*64..+63.
    //      B-frags loaded DIRECTLY from f32 embW2 (lane n=l15, k=qb*8+j),
    //      converted to f16 in registers — no transpose, no preprocess. ----
    {
        const f16x8 af0 = *(const f16x8*)(sA + l15*72 + qb*8);
        const f16x8 af1 = *(const f16x8*)(sA + l15*72 + 32 + qb*8);
        const float mwa = mixwa[0], mwb = mixwb[0], mb2v = mixb2[0];
        #pragma unroll
        for (int nt = 0; nt < 4; ++nt) {
            const int c = wv*64 + nt*16 + l15;
            const float* Wp = embW2 + (qb*8)*256 + c;
            f16x8 bf0, bf1;
            #pragma unroll
            for (int j = 0; j < 8; ++j) {
                bf0[j] = (f16)Wp[j*256];
                bf1[j] = (f16)Wp[j*256 + 8192];      // k += 32
            }
            v4f acc = {0.f, 0.f, 0.f, 0.f};
            acc = __builtin_amdgcn_mfma_f32_16x16x32_f16(af0, bf0, acc, 0, 0, 0);
            acc = __builtin_amdgcn_mfma_f32_16x16x32_f16(af1, bf1, acc, 0, 0, 0);
            const float b2c = embb2[c];
            const float s0 = acc[0]+b2c, s1 = acc[1]+b2c, s2 = acc[2]+b2c, s3 = acc[3]+b2c;
            float ev = mb2v;
            #pragma unroll
            for (int j = 0; j < 8; ++j) {
                float p = fmaf(s0, mixW1[j],
                          fmaf(s1, mixW1[8+j],
                          fmaf(s2, mixW1[16+j],
                          fmaf(s3, mixW1[24+j], mixb1[j]))));
                ev = fmaf(mwa*__sinf(p) + mwb*__cosf(p), mixW2[j], ev);
            }
            sE[qb*264 + c] = (f16)ev;
        }
    }
    __syncthreads();

    // ---- phase 3: wave wv owns feature tile fme = wv*16 + l15 ----
    const int fme = wv*16 + l15;

    // layer 0: [4 x 256] @ outW0 [256 x 64]  (A rows 4-15 garbage -> only their
    // own D rows, discarded; store qb==0 only)
    {
        v4f acc = {0.f, 0.f, 0.f, 0.f};
        const f16* Ae = sE + l15*264 + qb*8;
        #pragma unroll
        for (int kt = 0; kt < 8; ++kt) {
            const f16x8 af = *(const f16x8*)(Ae + kt*32);
            const float* Wp = outW0 + (kt*32 + qb*8)*64 + fme;
            f16x8 bf;
            #pragma unroll
            for (int j = 0; j < 8; ++j) bf[j] = (f16)Wp[j*64];
            acc = __builtin_amdgcn_mfma_f32_16x16x32_f16(af, bf, acc, 0, 0, 0);
        }
        if (qb == 0) {
            const float b0 = outb0[fme], wa = outwa0[0], wb = outwb0[0];
            #pragma unroll
            for (int r = 0; r < 4; ++r) {
                const float a = acc[r] + b0;
                sH[0][r*72 + fme] = (f16)(wa*__sinf(a) + wb*__cosf(a));
            }
        }
    }
    __syncthreads();

    // hidden x3 + f1: [4 x 64] @ [64 x 64]
    int cur = 0;
    #pragma unroll
    for (int i = 0; i < 4; ++i) {
        const float* Wg = (i < 3) ? (outWh + i*4096) : outWf1;
        v4f acc = {0.f, 0.f, 0.f, 0.f};
        #pragma unroll
        for (int kt = 0; kt < 2; ++kt) {
            const f16x8 af = *(const f16x8*)(sH[cur] + l15*72 + kt*32 + qb*8);
            const float* Wp = Wg + (kt*32 + qb*8)*64 + fme;
            f16x8 bf;
            #pragma unroll
            for (int j = 0; j < 8; ++j) bf[j] = (f16)Wp[j*64];
            acc = __builtin_amdgcn_mfma_f32_16x16x32_f16(af, bf, acc, 0, 0, 0);
        }
        if (qb == 0) {
            float bias, wa, wb;
            if (i < 3) { bias = outbh[i*64 + fme]; wa = outwah[i]; wb = outwbh[i]; }
            else       { bias = outbf1[fme];       wa = outwaf[0]; wb = outwbf[0]; }
            #pragma unroll
            for (int r = 0; r < 4; ++r) {
                const float a = acc[r] + bias;
                const float v = wa*__sinf(a) + wb*__cosf(a);
                if (i < 3) sH[cur^1][r*72 + fme] = (f16)v;
                else       sHf[r*65 + fme] = v;
            }
        }
        __syncthreads();
        cur ^= 1;
    }

    // ---- final 64 -> 3 (f32 weights) ----
    if (tid < 12) {
        const int s = tid / 3, o = tid - s*3;
        float a = outbf2[o];
        #pragma unroll 16
        for (int k = 0; k < 64; ++k)
            a = fmaf(sHf[s*65 + k], outWf2[k*3 + o], a);
        const int gn = n0 + s;
        if (gn < N) out[gn*3 + o] = a;
    }
}

extern "C" void kernel_launch(void* const* d_in, const int* in_sizes, int n_in,
                              void* d_out, int out_size, void* d_ws, size_t ws_size,
                              hipStream_t stream) {
    const float* x      = (const float*)d_in[0];
    const float* y      = (const float*)d_in[1];
    const float* t      = (const float*)d_in[2];
    const float* embW1  = (const float*)d_in[3];
    const float* embb1  = (const float*)d_in[4];
    const float* embwa  = (const float*)d_in[5];
    const float* embwb  = (const float*)d_in[6];
    const float* embW2  = (const float*)d_in[7];
    const float* embb2  = (const float*)d_in[8];
    const float* mixW1  = (const float*)d_in[9];
    const float* mixb1  = (const float*)d_in[10];
    const float* mixwa  = (const float*)d_in[11];
    const float* mixwb  = (const float*)d_in[12];
    const float* mixW2  = (const float*)d_in[13];
    const float* mixb2  = (const float*)d_in[14];
    const float* outW0  = (const float*)d_in[15];
    const float* outb0  = (const float*)d_in[16];
    const float* outwa0 = (const float*)d_in[17];
    const float* outwb0 = (const float*)d_in[18];
    const float* outWh  = (const float*)d_in[19];
    const float* outbh  = (const float*)d_in[20];
    const float* outwah = (const float*)d_in[21];
    const float* outwbh = (const float*)d_in[22];
    const float* outWf1 = (const float*)d_in[23];
    const float* outbf1 = (const float*)d_in[24];
    const float* outwaf = (const float*)d_in[25];
    const float* outwbf = (const float*)d_in[26];
    const float* outWf2 = (const float*)d_in[27];
    const float* outbf2 = (const float*)d_in[28];
    float* out = (float*)d_out;

    const int N = in_sizes[0];
    const int blocks = (N + 3) / 4;
    model_one<<<blocks, 256, 0, stream>>>(
        x, y, t,
        embW1, embb1, embwa, embwb, embW2, embb2,
        mixW1, mixb1, mixwa, mixwb, mixW2, mixb2,
        outW0, outb0, outwa0, outwb0,
        outWh, outbh, outwah, outwbh,
        outWf1, outbf1, outwaf, outwbf, outWf2, outbf2,
        out, N);
}